// Round 1
// baseline (353.897 us; speedup 1.0000x reference)
//
#include <hip/hip_runtime.h>

// ---------------------------------------------------------------------------
// SelfAttentionBlock: B=4, N=2048, D=1024. Reference contracts h AND d in the
// score einsum -> effectively single-head attention with head dim 1024.
//   QKV = X @ Wqkv^T            (8192x1024)@(3072x1024)^T
//   S_b = Q_b @ K_b^T * 0.125   per batch (2048x2048)
//   P   = softmax_rows(S)
//   O_b = P_b @ V_b             (via V transposed, B^T-pattern GEMM)
//   out = O @ Wout^T + b_out    fp32 output
// All GEMMs: bf16 inputs, fp32 MFMA accumulate (16x16x32_bf16), m97-style
// 128x128 tile, BK=32, global_load_lds width-16 staging.
// ---------------------------------------------------------------------------

typedef __bf16 bf16;
typedef __attribute__((ext_vector_type(8))) __bf16 bf16x8;
typedef __attribute__((ext_vector_type(4))) __bf16 bf16x4;
typedef __attribute__((ext_vector_type(4))) float f32x4;

#define BATCH 4
#define NTOK  2048
#define DIM   1024
#define MROWS (BATCH * NTOK)   // 8192
#define QKVC  (3 * DIM)        // 3072

__device__ __forceinline__ void async16(const bf16* g, bf16* l) {
  __builtin_amdgcn_global_load_lds(
      (const __attribute__((address_space(1))) void*)g,
      (__attribute__((address_space(3))) void*)l, 16, 0, 0);
}

// ---------------------------------------------------------------------------
// fp32 -> bf16 elementwise convert (n divisible by 4)
// ---------------------------------------------------------------------------
__global__ void f32_to_bf16(const float* __restrict__ in, bf16* __restrict__ out, int n) {
  int i = (blockIdx.x * blockDim.x + threadIdx.x) * 4;
  if (i < n) {
    float4 f = *(const float4*)(in + i);
    bf16x4 o;
    o.x = (bf16)f.x; o.y = (bf16)f.y; o.z = (bf16)f.z; o.w = (bf16)f.w;
    *(bf16x4*)(out + i) = o;
  }
}

// ---------------------------------------------------------------------------
// GEMM: C[i][j] = sum_k A[i][k] * B[j][k]   (both row-major, B^T pattern)
// MODE 0: store bf16.  MODE 1: store fp32 * scale.  MODE 2: store fp32 + bias.
// Grid: (N/128, M/128, batches). 256 threads.
// ---------------------------------------------------------------------------
template <int MODE>
__launch_bounds__(256)
__global__ void gemm_bt(const bf16* __restrict__ Aroot, const bf16* __restrict__ Broot,
                        void* __restrict__ Croot, const float* __restrict__ bias,
                        int K, int lda, int ldb, int ldc,
                        long strideA, long strideB, long strideC, float scale) {
  const bf16* A  = Aroot + (long)blockIdx.z * strideA;
  const bf16* Bm = Broot + (long)blockIdx.z * strideB;

  __shared__ alignas(16) bf16 As[128 * 32];
  __shared__ alignas(16) bf16 Bs[128 * 32];

  const int tid  = threadIdx.x;
  const int wave = tid >> 6, lane = tid & 63;
  const int wm = (wave >> 1) << 6;   // wave row offset in tile
  const int wn = (wave & 1) << 6;    // wave col offset in tile
  const int quad = lane >> 4, r16 = lane & 15;

  const long rowA = (long)blockIdx.y * 128;
  const long rowB = (long)blockIdx.x * 128;

  // staging: thread t loads 8 bf16 (16B); 2 instrs per tile cover 128 rows
  const int srow = tid >> 2;          // 0..63
  const int scol = (tid & 3) << 3;    // 0,8,16,24

  const bf16* ga0 = A  + (rowA + srow)      * (long)lda + scol;
  const bf16* ga1 = A  + (rowA + srow + 64) * (long)lda + scol;
  const bf16* gb0 = Bm + (rowB + srow)      * (long)ldb + scol;
  const bf16* gb1 = Bm + (rowB + srow + 64) * (long)ldb + scol;
  bf16* la0 = &As[srow * 32 + scol];
  bf16* la1 = &As[(srow + 64) * 32 + scol];
  bf16* lb0 = &Bs[srow * 32 + scol];
  bf16* lb1 = &Bs[(srow + 64) * 32 + scol];

  f32x4 acc[4][4] = {};

  for (int kt = 0; kt < K; kt += 32) {
    async16(ga0 + kt, la0);
    async16(ga1 + kt, la1);
    async16(gb0 + kt, lb0);
    async16(gb1 + kt, lb1);
    __syncthreads();   // drains vmcnt -> LDS tiles ready

    bf16x8 af[4], bfr[4];
#pragma unroll
    for (int i = 0; i < 4; ++i)
      af[i] = *(const bf16x8*)&As[(wm + i * 16 + r16) * 32 + quad * 8];
#pragma unroll
    for (int j = 0; j < 4; ++j)
      bfr[j] = *(const bf16x8*)&Bs[(wn + j * 16 + r16) * 32 + quad * 8];

#pragma unroll
    for (int i = 0; i < 4; ++i)
#pragma unroll
      for (int j = 0; j < 4; ++j)
        acc[i][j] = __builtin_amdgcn_mfma_f32_16x16x32_bf16(af[i], bfr[j], acc[i][j], 0, 0, 0);

    __syncthreads();   // all reads done before next stage overwrites
  }

  // epilogue: C/D layout col = lane&15, row = quad*4 + reg
#pragma unroll
  for (int i = 0; i < 4; ++i) {
    const long row0 = rowA + wm + i * 16 + quad * 4;
#pragma unroll
    for (int j = 0; j < 4; ++j) {
      const long col = rowB + wn + j * 16 + r16;
#pragma unroll
      for (int r = 0; r < 4; ++r) {
        float v = acc[i][j][r];
        if constexpr (MODE == 0) {
          bf16* C = (bf16*)Croot + (long)blockIdx.z * strideC;
          C[(row0 + r) * (long)ldc + col] = (bf16)v;
        } else if constexpr (MODE == 1) {
          float* C = (float*)Croot + (long)blockIdx.z * strideC;
          C[(row0 + r) * (long)ldc + col] = v * scale;
        } else {
          float* C = (float*)Croot + (long)blockIdx.z * strideC;
          C[(row0 + r) * (long)ldc + col] = v + bias[col];
        }
      }
    }
  }
}

// ---------------------------------------------------------------------------
// row softmax: S (fp32, rows of 2048) -> P (bf16). One block per row.
// ---------------------------------------------------------------------------
__global__ __launch_bounds__(256) void softmax_rows(const float* __restrict__ S,
                                                    bf16* __restrict__ P) {
  const long row = blockIdx.x;
  const float* s = S + row * (long)NTOK;
  const int tid = threadIdx.x;
  const int wave = tid >> 6, lane = tid & 63;

  float v[8];
#pragma unroll
  for (int k = 0; k < 8; ++k) v[k] = s[tid + k * 256];

  float mx = v[0];
#pragma unroll
  for (int k = 1; k < 8; ++k) mx = fmaxf(mx, v[k]);
#pragma unroll
  for (int off = 32; off >= 1; off >>= 1) mx = fmaxf(mx, __shfl_xor(mx, off, 64));

  __shared__ float red[4];
  if (lane == 0) red[wave] = mx;
  __syncthreads();
  mx = fmaxf(fmaxf(red[0], red[1]), fmaxf(red[2], red[3]));
  __syncthreads();   // everyone done reading red before reuse

  float sum = 0.f;
#pragma unroll
  for (int k = 0; k < 8; ++k) { v[k] = __expf(v[k] - mx); sum += v[k]; }
#pragma unroll
  for (int off = 32; off >= 1; off >>= 1) sum += __shfl_xor(sum, off, 64);
  if (lane == 0) red[wave] = sum;
  __syncthreads();
  sum = red[0] + red[1] + red[2] + red[3];
  const float inv = 1.f / sum;

  bf16* p = P + row * (long)NTOK;
#pragma unroll
  for (int k = 0; k < 8; ++k) p[tid + k * 256] = (bf16)(v[k] * inv);
}

// ---------------------------------------------------------------------------
// V transpose: per batch, QKV[:,2048:3072] (2048x1024, ld 3072) -> Vt (1024x2048)
// 64x64 LDS tile, pad 66 to kill bank conflicts.
// ---------------------------------------------------------------------------
__global__ __launch_bounds__(256) void transpose_v(const bf16* __restrict__ QKV,
                                                   bf16* __restrict__ Vt) {
  const int z = blockIdx.z;
  const bf16* src = QKV + (long)z * NTOK * QKVC + 2 * DIM;
  bf16* dst = Vt + (long)z * DIM * NTOK;

  __shared__ bf16 tile[64][66];
  const int d0 = blockIdx.x * 64;   // col in src (0..1023)
  const int m0 = blockIdx.y * 64;   // row in src (0..2047)
  const int tx = threadIdx.x & 63, ty = threadIdx.x >> 6;

  for (int r = ty; r < 64; r += 4)
    tile[r][tx] = src[(long)(m0 + r) * QKVC + d0 + tx];
  __syncthreads();
  for (int r = ty; r < 64; r += 4)
    dst[(long)(d0 + r) * NTOK + m0 + tx] = tile[tx][r];
}

// ---------------------------------------------------------------------------
extern "C" void kernel_launch(void* const* d_in, const int* in_sizes, int n_in,
                              void* d_out, int out_size, void* d_ws, size_t ws_size,
                              hipStream_t stream) {
  const float* x      = (const float*)d_in[0];   // (4,2048,1024)
  const float* w_qkv  = (const float*)d_in[1];   // (3072,1024)
  const float* w_out  = (const float*)d_in[2];   // (1024,1024)
  const float* b_out  = (const float*)d_in[3];   // (1024,)
  float* out = (float*)d_out;                    // (4,2048,1024) fp32

  // workspace layout (bytes) — total exactly 200 MiB
  char* w = (char*)d_ws;
  bf16*  Xbf   = (bf16*)(w);                          // 8192*1024*2   = 16 MiB
  bf16*  Wqkvb = (bf16*)(w + 16777216);               // 3072*1024*2   =  6 MiB
  bf16*  Woutb = (bf16*)(w + 23068672);               // 1024*1024*2   =  2 MiB
  bf16*  QKV   = (bf16*)(w + 25165824);               // 8192*3072*2   = 48 MiB
  float* S     = (float*)(w + 75497472);              // 4*2048*2048*4 = 64 MiB
  bf16*  P     = (bf16*)(w + 142606336);              // 4*2048*2048*2 = 32 MiB
  bf16*  Vt    = (bf16*)(w + 176160768);              // 4*1024*2048*2 = 16 MiB
  bf16*  O     = (bf16*)(w + 192937984);              // 8192*1024*2   = 16 MiB

  // 1) fp32 -> bf16 converts
  f32_to_bf16<<<(MROWS * DIM / 4 + 255) / 256, 256, 0, stream>>>(x, Xbf, MROWS * DIM);
  f32_to_bf16<<<(QKVC * DIM / 4 + 255) / 256, 256, 0, stream>>>(w_qkv, Wqkvb, QKVC * DIM);
  f32_to_bf16<<<(DIM * DIM / 4 + 255) / 256, 256, 0, stream>>>(w_out, Woutb, DIM * DIM);

  // 2) QKV = X @ Wqkv^T -> bf16 (8192 x 3072)
  gemm_bt<0><<<dim3(QKVC / 128, MROWS / 128, 1), 256, 0, stream>>>(
      Xbf, Wqkvb, QKV, nullptr, DIM, DIM, DIM, QKVC, 0, 0, 0, 1.f);

  // 3) S_b = Q_b @ K_b^T * 0.125 -> fp32 (per batch 2048 x 2048)
  gemm_bt<1><<<dim3(NTOK / 128, NTOK / 128, BATCH), 256, 0, stream>>>(
      QKV, QKV + DIM, S, nullptr, DIM, QKVC, QKVC, NTOK,
      (long)NTOK * QKVC, (long)NTOK * QKVC, (long)NTOK * NTOK, 0.125f);

  // 4) P = softmax_rows(S) -> bf16
  softmax_rows<<<BATCH * NTOK, 256, 0, stream>>>(S, P);

  // 5) Vt_b = V_b^T  (1024 x 2048 per batch)
  transpose_v<<<dim3(DIM / 64, NTOK / 64, BATCH), 256, 0, stream>>>(QKV, Vt);

  // 6) O_b = P_b @ Vt_b^T -> bf16 (2048 x 1024 per batch)
  gemm_bt<0><<<dim3(DIM / 128, NTOK / 128, BATCH), 256, 0, stream>>>(
      P, Vt, O, nullptr, NTOK, NTOK, NTOK, DIM,
      (long)NTOK * NTOK, (long)DIM * NTOK, (long)NTOK * DIM, 1.f);

  // 7) out = O @ Wout^T + b_out -> fp32
  gemm_bt<2><<<dim3(DIM / 128, MROWS / 128, 1), 256, 0, stream>>>(
      O, Woutb, out, b_out, DIM, DIM, DIM, DIM, 0, 0, 0, 1.f);
}

// Round 2
// 337.545 us; speedup vs baseline: 1.0484x; 1.0484x over previous
//
#include <hip/hip_runtime.h>

// ---------------------------------------------------------------------------
// SelfAttentionBlock: B=4, N=2048, D=1024. Single-head attention, head dim 1024.
//   QKV = X @ Wqkv^T                  (8192x1024)@(3072x1024)^T
//   S_b = Q_b @ K_b^T * 0.125         per batch (2048x2048), fp32
//   P   = softmax_rows(S)             bf16
//   V''_b = Wout @ V_b^T              (1024x2048) per batch  [B^T GEMM, no transpose]
//   out_b = P_b @ V''_b^T + b_out     fp32   ( == (P@V)@Wout^T + b )
// GEMM: bf16 in, fp32 MFMA acc, 32x32x16 MFMA, 128x128 tile, BK=32,
// global_load_lds width-16 staging (m97 structure).
// ---------------------------------------------------------------------------

typedef __bf16 bf16;
typedef __attribute__((ext_vector_type(8))) __bf16 bf16x8;
typedef __attribute__((ext_vector_type(4))) __bf16 bf16x4;
typedef __attribute__((ext_vector_type(16))) float f32x16;

#define BATCH 4
#define NTOK  2048
#define DIM   1024
#define MROWS (BATCH * NTOK)   // 8192
#define QKVC  (3 * DIM)        // 3072

__device__ __forceinline__ void async16(const bf16* g, bf16* l) {
  __builtin_amdgcn_global_load_lds(
      (const __attribute__((address_space(1))) void*)g,
      (__attribute__((address_space(3))) void*)l, 16, 0, 0);
}

// ---------------------------------------------------------------------------
__global__ void f32_to_bf16(const float* __restrict__ in, bf16* __restrict__ out, int n) {
  int i = (blockIdx.x * blockDim.x + threadIdx.x) * 4;
  if (i < n) {
    float4 f = *(const float4*)(in + i);
    bf16x4 o;
    o.x = (bf16)f.x; o.y = (bf16)f.y; o.z = (bf16)f.z; o.w = (bf16)f.w;
    *(bf16x4*)(out + i) = o;
  }
}

// ---------------------------------------------------------------------------
// GEMM: C[i][j] = sum_k A[i][k] * B[j][k]   (both row-major, B^T pattern)
// 32x32x16 bf16 MFMA. Wave tiling: 4 waves in 2x2, each wave 64x64 = 2x2 of
// 32x32 tiles. A-frag: A[m=lane&31][k=8*(lane>>5)+e]; B-frag symmetric.
// C/D: col=lane&31, row=(reg&3)+8*(reg>>2)+4*(lane>>5)  [m74/m101 verified].
// MODE 0: store bf16.  MODE 1: fp32 * scale.  MODE 2: fp32 + bias.
// ---------------------------------------------------------------------------
template <int MODE>
__launch_bounds__(256)
__global__ void gemm_bt(const bf16* __restrict__ Aroot, const bf16* __restrict__ Broot,
                        void* __restrict__ Croot, const float* __restrict__ bias,
                        int K, int lda, int ldb, int ldc,
                        long strideA, long strideB, long strideC, float scale) {
  const bf16* A  = Aroot + (long)blockIdx.z * strideA;
  const bf16* Bm = Broot + (long)blockIdx.z * strideB;

  __shared__ alignas(16) bf16 As[128 * 32];
  __shared__ alignas(16) bf16 Bs[128 * 32];

  const int tid  = threadIdx.x;
  const int wave = tid >> 6, lane = tid & 63;
  const int wm = (wave >> 1) << 6;   // wave row offset in tile
  const int wn = (wave & 1) << 6;    // wave col offset in tile
  const int l31 = lane & 31, half = lane >> 5;

  const long rowA = (long)blockIdx.y * 128;
  const long rowB = (long)blockIdx.x * 128;

  // staging: thread t loads 8 bf16 (16B); 2 instrs per operand cover 128 rows
  const int srow = tid >> 2;          // 0..63
  const int scol = (tid & 3) << 3;    // 0,8,16,24

  const bf16* ga0 = A  + (rowA + srow)      * (long)lda + scol;
  const bf16* ga1 = A  + (rowA + srow + 64) * (long)lda + scol;
  const bf16* gb0 = Bm + (rowB + srow)      * (long)ldb + scol;
  const bf16* gb1 = Bm + (rowB + srow + 64) * (long)ldb + scol;
  bf16* la0 = &As[srow * 32 + scol];
  bf16* la1 = &As[(srow + 64) * 32 + scol];
  bf16* lb0 = &Bs[srow * 32 + scol];
  bf16* lb1 = &Bs[(srow + 64) * 32 + scol];

  f32x16 acc[2][2] = {};

  for (int kt = 0; kt < K; kt += 32) {
    async16(ga0 + kt, la0);
    async16(ga1 + kt, la1);
    async16(gb0 + kt, lb0);
    async16(gb1 + kt, lb1);
    __syncthreads();   // drains vmcnt -> LDS tiles ready

    bf16x8 af[2][2], bfm[2][2];
#pragma unroll
    for (int ti = 0; ti < 2; ++ti)
#pragma unroll
      for (int s = 0; s < 2; ++s)
        af[ti][s] = *(const bf16x8*)&As[(wm + ti * 32 + l31) * 32 + s * 16 + half * 8];
#pragma unroll
    for (int tj = 0; tj < 2; ++tj)
#pragma unroll
      for (int s = 0; s < 2; ++s)
        bfm[tj][s] = *(const bf16x8*)&Bs[(wn + tj * 32 + l31) * 32 + s * 16 + half * 8];

#pragma unroll
    for (int s = 0; s < 2; ++s)
#pragma unroll
      for (int ti = 0; ti < 2; ++ti)
#pragma unroll
        for (int tj = 0; tj < 2; ++tj)
          acc[ti][tj] = __builtin_amdgcn_mfma_f32_32x32x16_bf16(
              af[ti][s], bfm[tj][s], acc[ti][tj], 0, 0, 0);

    __syncthreads();   // all reads done before next stage overwrites
  }

  // epilogue
#pragma unroll
  for (int ti = 0; ti < 2; ++ti) {
#pragma unroll
    for (int tj = 0; tj < 2; ++tj) {
      const long col = rowB + wn + tj * 32 + l31;
#pragma unroll
      for (int r = 0; r < 16; ++r) {
        const long row = rowA + wm + ti * 32 + (r & 3) + 8 * (r >> 2) + 4 * half;
        float v = acc[ti][tj][r];
        if constexpr (MODE == 0) {
          bf16* C = (bf16*)Croot + (long)blockIdx.z * strideC;
          C[row * (long)ldc + col] = (bf16)v;
        } else if constexpr (MODE == 1) {
          float* C = (float*)Croot + (long)blockIdx.z * strideC;
          C[row * (long)ldc + col] = v * scale;
        } else {
          float* C = (float*)Croot + (long)blockIdx.z * strideC;
          C[row * (long)ldc + col] = v + bias[col];
        }
      }
    }
  }
}

// ---------------------------------------------------------------------------
// row softmax: S (fp32, rows of 2048) -> P (bf16). One block per row.
// ---------------------------------------------------------------------------
__global__ __launch_bounds__(256) void softmax_rows(const float* __restrict__ S,
                                                    bf16* __restrict__ P) {
  const long row = blockIdx.x;
  const float* s = S + row * (long)NTOK;
  const int tid = threadIdx.x;
  const int wave = tid >> 6, lane = tid & 63;

  float v[8];
#pragma unroll
  for (int k = 0; k < 8; ++k) v[k] = s[tid + k * 256];

  float mx = v[0];
#pragma unroll
  for (int k = 1; k < 8; ++k) mx = fmaxf(mx, v[k]);
#pragma unroll
  for (int off = 32; off >= 1; off >>= 1) mx = fmaxf(mx, __shfl_xor(mx, off, 64));

  __shared__ float red[4];
  if (lane == 0) red[wave] = mx;
  __syncthreads();
  mx = fmaxf(fmaxf(red[0], red[1]), fmaxf(red[2], red[3]));
  __syncthreads();

  float sum = 0.f;
#pragma unroll
  for (int k = 0; k < 8; ++k) { v[k] = __expf(v[k] - mx); sum += v[k]; }
#pragma unroll
  for (int off = 32; off >= 1; off >>= 1) sum += __shfl_xor(sum, off, 64);
  if (lane == 0) red[wave] = sum;
  __syncthreads();
  sum = red[0] + red[1] + red[2] + red[3];
  const float inv = 1.f / sum;

  bf16* p = P + row * (long)NTOK;
#pragma unroll
  for (int k = 0; k < 8; ++k) p[tid + k * 256] = (bf16)(v[k] * inv);
}

// ---------------------------------------------------------------------------
extern "C" void kernel_launch(void* const* d_in, const int* in_sizes, int n_in,
                              void* d_out, int out_size, void* d_ws, size_t ws_size,
                              hipStream_t stream) {
  const float* x      = (const float*)d_in[0];   // (4,2048,1024)
  const float* w_qkv  = (const float*)d_in[1];   // (3072,1024)
  const float* w_out  = (const float*)d_in[2];   // (1024,1024)
  const float* b_out  = (const float*)d_in[3];   // (1024,)
  float* out = (float*)d_out;                    // (4,2048,1024) fp32

  // workspace layout (bytes) — total 184 MiB
  char* w = (char*)d_ws;
  bf16*  Xbf   = (bf16*)(w);                          // 8192*1024*2   = 16 MiB
  bf16*  Wqkvb = (bf16*)(w + 16777216);               // 3072*1024*2   =  6 MiB
  bf16*  Woutb = (bf16*)(w + 23068672);               // 1024*1024*2   =  2 MiB
  bf16*  QKV   = (bf16*)(w + 25165824);               // 8192*3072*2   = 48 MiB
  float* S     = (float*)(w + 75497472);              // 4*2048*2048*4 = 64 MiB
  bf16*  P     = (bf16*)(w + 142606336);              // 4*2048*2048*2 = 32 MiB
  bf16*  Vpp   = (bf16*)(w + 176160768);              // 4*1024*2048*2 = 16 MiB

  // 1) fp32 -> bf16 converts
  f32_to_bf16<<<(MROWS * DIM / 4 + 255) / 256, 256, 0, stream>>>(x, Xbf, MROWS * DIM);
  f32_to_bf16<<<(QKVC * DIM / 4 + 255) / 256, 256, 0, stream>>>(w_qkv, Wqkvb, QKVC * DIM);
  f32_to_bf16<<<(DIM * DIM / 4 + 255) / 256, 256, 0, stream>>>(w_out, Woutb, DIM * DIM);

  // 2) QKV = X @ Wqkv^T -> bf16 (8192 x 3072)
  gemm_bt<0><<<dim3(QKVC / 128, MROWS / 128, 1), 256, 0, stream>>>(
      Xbf, Wqkvb, QKV, nullptr, DIM, DIM, DIM, QKVC, 0, 0, 0, 1.f);

  // 3) S_b = Q_b @ K_b^T * 0.125 -> fp32 (per batch 2048 x 2048)
  gemm_bt<1><<<dim3(NTOK / 128, NTOK / 128, BATCH), 256, 0, stream>>>(
      QKV, QKV + DIM, S, nullptr, DIM, QKVC, QKVC, NTOK,
      (long)NTOK * QKVC, (long)NTOK * QKVC, (long)NTOK * NTOK, 0.125f);

  // 4) P = softmax_rows(S) -> bf16
  softmax_rows<<<BATCH * NTOK, 256, 0, stream>>>(S, P);

  // 5) V''_b = Wout @ V_b^T -> bf16 (1024 x 2048 per batch)
  //    C[i][j] = sum_k Wout[i][k] * V_b[j][k]
  gemm_bt<0><<<dim3(NTOK / 128, DIM / 128, BATCH), 256, 0, stream>>>(
      Woutb, QKV + 2 * DIM, Vpp, nullptr, DIM, DIM, QKVC, NTOK,
      0, (long)NTOK * QKVC, (long)DIM * NTOK, 1.f);

  // 6) out_b = P_b @ V''_b^T + b_out -> fp32 (2048 x 1024 per batch)
  gemm_bt<2><<<dim3(DIM / 128, NTOK / 128, BATCH), 256, 0, stream>>>(
      P, Vpp, out, b_out, NTOK, NTOK, NTOK, DIM,
      (long)NTOK * NTOK, (long)DIM * NTOK, (long)NTOK * DIM, 1.f);
}